// Round 17
// baseline (128.641 us; speedup 1.0000x reference)
//
#include <hip/hip_runtime.h>

#define H 12
#define T 2048
#define D 768
#define NBT 4096            // B*T
#define SCALE 0.125f
#define DECAY_F 0.99f
#define NCHK 40             // split-s chunk slots per bh (8 tiles each)
#define NBLK_ATTN (24 * NCHK)
#define NBLK_MS1 192        // 24 bh x 8 chunks of 256 timesteps
#define EXP2C 0.18033688011f   // 0.125 * log2(e)

typedef __attribute__((ext_vector_type(8))) short bf16x8;
typedef __attribute__((ext_vector_type(4))) float f32x4;
typedef __attribute__((ext_vector_type(16))) float f32x16;

static __device__ __forceinline__ ushort f2bf(float f) {
  union { float f; unsigned u; } v; v.f = f;
  unsigned r = (v.u + 0x7FFFu + ((v.u >> 16) & 1u)) >> 16;
  return (ushort)r;
}
static __device__ __forceinline__ float bf2f(ushort u) {
  union { unsigned u; float f; } v; v.u = ((unsigned)u) << 16;
  return v.f;
}
static __device__ __forceinline__ unsigned cvtpk(float lo, float hi) {
  unsigned r;
  asm("v_cvt_pk_bf16_f32 %0, %1, %2" : "=v"(r) : "v"(lo), "v"(hi));
  return r;
}
static __device__ __forceinline__ void swap32(unsigned &a, unsigned &b) {
  asm("v_permlane32_swap_b32 %0, %1" : "+v"(a), "+v"(b));
}

static __device__ __forceinline__ void gload16(const void* g, void* s) {
  __builtin_amdgcn_global_load_lds(
      (const __attribute__((address_space(1))) unsigned int*)g,
      (__attribute__((address_space(3))) unsigned int*)s, 16, 0, 0);
}

// ---------------- cast x + all weights to bf16 (flat segmented) ----------
__global__ __launch_bounds__(256) void cast_all(
    const float* __restrict__ x, const float* __restrict__ qkv_w,
    const float* __restrict__ memv_w, const float* __restrict__ out_w,
    const float* __restrict__ w1w, const float* __restrict__ w2w,
    const float* __restrict__ w1r, const float* __restrict__ w2r,
    const float* __restrict__ memg_w, ushort* __restrict__ dst)
{
  const size_t i8 = ((size_t)blockIdx.x * 256 + threadIdx.x) * 8;
  const float* src; size_t off;
  if      (i8 < 3145728) { src = x;      off = i8; }
  else if (i8 < 4915200) { src = qkv_w;  off = i8 - 3145728; }
  else if (i8 < 5505024) { src = memv_w; off = i8 - 4915200; }
  else if (i8 < 5541888) { src = w1w;    off = i8 - 5505024; }
  else if (i8 < 5578752) { src = w2w;    off = i8 - 5541888; }
  else if (i8 < 5615616) { src = w1r;    off = i8 - 5578752; }
  else if (i8 < 5652480) { src = w2r;    off = i8 - 5615616; }
  else if (i8 < 5661696) { src = memg_w; off = i8 - 5652480; }
  else if (i8 < 5701632) { *(uint4*)(dst + i8) = make_uint4(0, 0, 0, 0); return; }
  else                   { src = out_w;  off = i8 - 5701632; }
  const float4 a = *(const float4*)(src + off);
  const float4 b = *(const float4*)(src + off + 4);
  bf16x8 o;
  o[0] = (short)f2bf(a.x); o[1] = (short)f2bf(a.y);
  o[2] = (short)f2bf(a.z); o[3] = (short)f2bf(a.w);
  o[4] = (short)f2bf(b.x); o[5] = (short)f2bf(b.y);
  o[6] = (short)f2bf(b.z); o[7] = (short)f2bf(b.w);
  *(bf16x8*)(dst + i8) = o;
}

// ============ 8-phase 256x256 MFMA GEMM (mega epilogue) ===================
__global__ __launch_bounds__(512, 2) void gemm8_mega(
    const ushort* __restrict__ A, const ushort* __restrict__ W,
    const float* __restrict__ qkv_b, const float* __restrict__ memv_b,
    ushort* __restrict__ memvp, float* __restrict__ pw,
    float* __restrict__ pmemg,
    ushort* __restrict__ Qb, ushort* __restrict__ Kb, ushort* __restrict__ Vtb)
{
  __shared__ ushort lds[65536];   // 128 KiB
  const int tid = threadIdx.x;
  const int w = tid >> 6, l = tid & 63;
  const int wm = w >> 2, wn = w & 3;
  const int l15 = l & 15, l4 = l >> 4;

  int bid = blockIdx.x;
  bid = (bid & 7) * 26 + (bid >> 3);
  const int bx = bid % 13, by = bid / 13;
  const int bm = by * 256, bn = bx * 256;

  f32x4 acc[8][4];
#pragma unroll
  for (int i = 0; i < 8; i++)
#pragma unroll
    for (int j = 0; j < 4; j++) acc[i][j] = (f32x4){0.f, 0.f, 0.f, 0.f};

  auto stage = [&](int s, int isB, int h, int kt) {
    const ushort* src = (isB ? W + (size_t)bn * 768 : A + (size_t)bm * 768);
#pragma unroll
    for (int j = 0; j < 2; j++) {
      const int chunk = j * 512 + tid;
      const int r = chunk >> 3, c = chunk & 7;
      const int csrc = c ^ (r & 7);
      gload16(src + (size_t)(h * 128 + r) * 768 + kt * 64 + csrc * 8,
              (char*)lds + s * 65536 + isB * 32768 + h * 16384
                         + (size_t)(j * 512 + w * 64) * 16);
    }
  };
  auto rdA = [&](int s, int mi, int ks) -> bf16x8 {
    const int row = wm * 128 + mi * 16 + l15;
    const int ch = (ks * 4 + l4) ^ (l15 & 7);
    return *(const bf16x8*)((const char*)lds + s * 65536 + row * 128 + ch * 16);
  };
  auto rdB = [&](int s, int ni, int ks) -> bf16x8 {
    const int row = wn * 64 + ni * 16 + l15;
    const int ch = (ks * 4 + l4) ^ (l15 & 7);
    return *(const bf16x8*)((const char*)lds + s * 65536 + 32768 + row * 128 + ch * 16);
  };

  stage(0, 1, 0, 0); stage(0, 1, 1, 0); stage(0, 0, 0, 0); stage(0, 0, 1, 0);

#define MFMA_QUAD(mb, ks)                                                      \
  {                                                                            \
    __builtin_amdgcn_s_setprio(1);                                             \
    _Pragma("unroll")                                                          \
    for (int mi = 0; mi < 4; mi++) {                                           \
      const bf16x8 av = rdA(s, (mb) + mi, (ks));                               \
      acc[(mb)+mi][0] = __builtin_amdgcn_mfma_f32_16x16x32_bf16(av, bq0, acc[(mb)+mi][0], 0, 0, 0); \
      acc[(mb)+mi][1] = __builtin_amdgcn_mfma_f32_16x16x32_bf16(av, bq1, acc[(mb)+mi][1], 0, 0, 0); \
      acc[(mb)+mi][2] = __builtin_amdgcn_mfma_f32_16x16x32_bf16(av, bq2, acc[(mb)+mi][2], 0, 0, 0); \
      acc[(mb)+mi][3] = __builtin_amdgcn_mfma_f32_16x16x32_bf16(av, bq3, acc[(mb)+mi][3], 0, 0, 0); \
    }                                                                          \
    __builtin_amdgcn_s_setprio(0);                                             \
  }

  for (int t = 0; t < 12; t++) {
    const int s = t & 1, sn = s ^ 1;
    const int ktn = (t + 1) % 12;
    bf16x8 bq0, bq1, bq2, bq3;
    stage(sn, 1, 0, ktn);
    asm volatile("s_waitcnt vmcnt(2)" ::: "memory");
    __builtin_amdgcn_s_barrier();
    __builtin_amdgcn_sched_barrier(0);
    bq0 = rdB(s, 0, 0); bq1 = rdB(s, 1, 0); bq2 = rdB(s, 2, 0); bq3 = rdB(s, 3, 0);
    MFMA_QUAD(0, 0);
    __builtin_amdgcn_s_barrier();
    stage(sn, 1, 1, ktn);
    MFMA_QUAD(4, 0);
    __builtin_amdgcn_s_barrier();
    stage(sn, 0, 0, ktn);
    bq0 = rdB(s, 0, 1); bq1 = rdB(s, 1, 1); bq2 = rdB(s, 2, 1); bq3 = rdB(s, 3, 1);
    MFMA_QUAD(0, 1);
    __builtin_amdgcn_s_barrier();
    stage(sn, 0, 1, ktn);
    MFMA_QUAD(4, 1);
    __builtin_amdgcn_s_barrier();
  }

#pragma unroll
  for (int mi = 0; mi < 8; mi++) {
    const int row0 = bm + wm * 128 + mi * 16 + l4 * 4;
    const int b = row0 >> 11, tl = row0 & (T - 1);
#pragma unroll
    for (int ni = 0; ni < 4; ni++) {
      const int col = bn + wn * 64 + ni * 16 + l15;
      const f32x4 a4 = acc[mi][ni];
      if (col < 2304) {
        const float bv = qkv_b[col];
        const int sec = col / 768, cm = col % 768;
        const int h = cm >> 6, d = cm & 63;
        if (sec < 2) {
          ushort* dst = sec ? Kb : Qb;
#pragma unroll
          for (int r = 0; r < 4; r++)
            dst[((size_t)(b * H + h) * T + tl + r) * 64 + d] = f2bf(a4[r] + bv);
        } else {
          uint2 u;
          u.x = (unsigned)f2bf(a4[0] + bv) | ((unsigned)f2bf(a4[1] + bv) << 16);
          u.y = (unsigned)f2bf(a4[2] + bv) | ((unsigned)f2bf(a4[3] + bv) << 16);
          *(uint2*)(Vtb + ((size_t)(b * H + h) * 64 + d) * T + tl) = u;
        }
      } else if (col < 3072) {
        const int c2 = col - 2304;
        const float bv = memv_b[c2];
#pragma unroll
        for (int r = 0; r < 4; r++)
          memvp[(size_t)(row0 + r) * 768 + c2] = f2bf(a4[r] + bv);
      } else if (col < 3276) {
        const int c2 = col - 3072;
        if (c2 < 192) {
          float* pb = pw + (size_t)(c2 / 48) * (H * NBT * 4);
          const int hh = (c2 % 48) >> 2, comp = c2 & 3;
#pragma unroll
          for (int r = 0; r < 4; r++)
            pb[((size_t)hh * NBT + row0 + r) * 4 + comp] = a4[r];
        } else {
#pragma unroll
          for (int r = 0; r < 4; r++)
            pmemg[(size_t)(c2 - 192) * NBT + row0 + r] = a4[r];
        }
      }
    }
  }
}

// ---------------- 128x128 MFMA GEMM (fp32 C + bias) — out-projection ------
__global__ __launch_bounds__(256) void gemm_mfma128(
    const ushort* __restrict__ A, const ushort* __restrict__ W,
    const float* __restrict__ bias, float* __restrict__ C, int ldc)
{
  __shared__ ushort A_lds[128 * 64];
  __shared__ ushort B_lds[128 * 64];
  const int tid = threadIdx.x;
  const int w = tid >> 6, l = tid & 63;
  const int wm = w >> 1, wn = w & 1;
  const int bm = blockIdx.y * 128, bn = blockIdx.x * 128;
  const int l15 = l & 15, l4 = l >> 4;

  f32x4 acc[4][4];
#pragma unroll
  for (int i = 0; i < 4; i++)
#pragma unroll
    for (int j = 0; j < 4; j++) acc[i][j] = (f32x4){0.f, 0.f, 0.f, 0.f};

  const int srow = w * 32 + (l >> 3);
  const int scol = (l & 7) * 8;
  const ushort* Ag = A + (size_t)(bm + srow) * 768 + scol;
  const ushort* Wg = W + (size_t)(bn + srow) * 768 + scol;
  ushort* Asl = &A_lds[(w * 32) * 64];
  ushort* Bsl = &B_lds[(w * 32) * 64];

  for (int k0 = 0; k0 < 768; k0 += 64) {
#pragma unroll
    for (int i = 0; i < 4; i++) {
      gload16(Ag + k0 + i * 8 * 768, Asl + i * 8 * 64);
      gload16(Wg + k0 + i * 8 * 768, Bsl + i * 8 * 64);
    }
    __syncthreads();
#pragma unroll
    for (int ks = 0; ks < 2; ks++) {
      bf16x8 af[4], bfr[4];
#pragma unroll
      for (int i = 0; i < 4; i++) {
        af[i]  = *(const bf16x8*)&A_lds[(wm * 64 + i * 16 + l15) * 64 + ks * 32 + l4 * 8];
        bfr[i] = *(const bf16x8*)&B_lds[(wn * 64 + i * 16 + l15) * 64 + ks * 32 + l4 * 8];
      }
#pragma unroll
      for (int mi = 0; mi < 4; mi++)
#pragma unroll
        for (int ni = 0; ni < 4; ni++)
          acc[mi][ni] = __builtin_amdgcn_mfma_f32_16x16x32_bf16(af[mi], bfr[ni], acc[mi][ni], 0, 0, 0);
    }
    __syncthreads();
  }
#pragma unroll
  for (int mi = 0; mi < 4; mi++) {
    const int row0 = bm + wm * 64 + mi * 16 + l4 * 4;
#pragma unroll
    for (int ni = 0; ni < 4; ni++) {
      const int col = bn + wn * 64 + ni * 16 + l15;
      const float bv = bias[col];
#pragma unroll
      for (int r = 0; r < 4; r++)
        C[(size_t)(row0 + r) * ldc + col] = acc[mi][ni][r] + bv;
    }
  }
}

// ---------------- Plucker memory pass 1: parallel per-timestep -----------
__device__ __forceinline__ void ext_norm6(const float4 a, const float4 b, float* L)
{
  L[0] = a.x * b.y - a.y * b.x;
  L[1] = a.x * b.z - a.z * b.x;
  L[2] = a.x * b.w - a.w * b.x;
  L[3] = a.y * b.z - a.z * b.y;
  L[4] = a.y * b.w - a.w * b.y;
  L[5] = a.z * b.w - a.w * b.z;
  float n2 = L[0]*L[0] + L[1]*L[1] + L[2]*L[2] + L[3]*L[3] + L[4]*L[4] + L[5]*L[5];
  float n = fmaxf(sqrtf(n2), 1e-12f);
  float inv = 1.f / n;
#pragma unroll
  for (int i = 0; i < 6; i++) L[i] *= inv;
}

// pw: [4][H][NBT][4] f32 head-major. 192 blocks: bh = bb>>3, chunk = bb&7.
// Thread = 1 timestep. Writes Rp[bh][2048][8] = {R0..R5, part1, 0} and
// G[bh][chunk][21] = inclusive end-of-chunk carry.  (verified round 13)
static __device__ void memscan1_body(
    int bb, char* smem, const float* __restrict__ pw,
    float* __restrict__ Rp, float* __restrict__ G)
{
  const int bh = bb >> 3, chunk = bb & 7;
  const int b = bh / H, h = bh % H;
  const int tid = threadIdx.x;
  float (*S)[22] = (float(*)[22])smem;
  const int t = chunk * 256 + tid;
  const size_t hb = (size_t)h * NBT + (size_t)b * T;
  const float* pw1w = pw + 0 * (size_t)(H * NBT * 4) + hb * 4;
  const float* pw2w = pw + 1 * (size_t)(H * NBT * 4) + hb * 4;
  const float* pw1r = pw + 2 * (size_t)(H * NBT * 4) + hb * 4;
  const float* pw2r = pw + 3 * (size_t)(H * NBT * 4) + hb * 4;

  float Cm[21];
#pragma unroll
  for (int c = 0; c < 21; c++) Cm[c] = 0.f;
  {
    const float4 w2 = *(const float4*)(pw2w + (size_t)t * 4);
    const int offs[4] = {1, 2, 4, 8};
#pragma unroll
    for (int oi = 0; oi < 4; oi++) {
      const int off = offs[oi];
      if (t >= off) {
        const float4 w1 = *(const float4*)(pw1w + (size_t)(t - off) * 4);
        float L[6];
        ext_norm6(w1, w2, L);
        const float Jv[6] = { L[5], -L[4], L[3], L[2], -L[1], L[0] };
        int c = 0;
#pragma unroll
        for (int p = 0; p < 6; p++)
#pragma unroll
          for (int q = p; q < 6; q++) { Cm[c] += Jv[p] * Jv[q]; c++; }
      }
    }
  }
  float R[6];
  {
    const float4 r1 = *(const float4*)(pw1r + (size_t)t * 4);
    const float4 r2 = *(const float4*)(pw2r + (size_t)t * 4);
    ext_norm6(r1, r2, R);
  }

#pragma unroll
  for (int c = 0; c < 21; c++) S[tid][c] = Cm[c];
  __syncthreads();
  float pd = DECAY_F;
  for (int off = 1; off < 256; off <<= 1) {
    float tmpv[21];
#pragma unroll
    for (int c = 0; c < 21; c++) tmpv[c] = (tid >= off) ? S[tid - off][c] : 0.f;
    __syncthreads();
#pragma unroll
    for (int c = 0; c < 21; c++) S[tid][c] += pd * tmpv[c];
    __syncthreads();
    pd *= pd;
  }
  float P[21];
#pragma unroll
  for (int c = 0; c < 21; c++) P[c] = (tid > 0) ? DECAY_F * S[tid - 1][c] : 0.f;

  float part1 = 0.f;
  {
    int c = 0;
#pragma unroll
    for (int p = 0; p < 6; p++) {
      part1 += P[c] * R[p] * R[p]; c++;
#pragma unroll
      for (int q = p + 1; q < 6; q++) { part1 += 2.f * P[c] * R[p] * R[q]; c++; }
    }
  }
  float* rp = Rp + ((size_t)bh * T + t) * 8;
  *(float4*)rp = make_float4(R[0], R[1], R[2], R[3]);
  *(float4*)(rp + 4) = make_float4(R[4], R[5], part1, 0.f);
  if (tid < 21)
    G[((size_t)bh * 8 + chunk) * 21 + tid] = S[255][tid];
}

// ------ fused: memscan1 (blocks 0-191, first) + flash attention ----------
// attn: split-8 chunks, heavy-first decode (ci2 = 39 - abid%40).
__global__ __launch_bounds__(256) void attn_memscan(
    const ushort* __restrict__ Qb, const ushort* __restrict__ Kb,
    const ushort* __restrict__ Vtb, ushort* __restrict__ o_part,
    float* __restrict__ rs_part,
    const float* __restrict__ pw, float* __restrict__ Rp, float* __restrict__ G)
{
  __shared__ __align__(16) char smem[36864];   // attn: K/V tiles; memscan1: S

  if (blockIdx.x < NBLK_MS1) {
    memscan1_body(blockIdx.x, smem, pw, Rp, G);
    return;
  }
  const int abid = blockIdx.x - NBLK_MS1;

  typedef ushort row72[72];
  row72* K_lds = (row72*)smem;                  // [128][72]
  row72* V_lds = (row72*)(smem + 18432);        // [128][72]

  const int bh = abid / NCHK;
  const int ci2 = (NCHK - 1) - (abid % NCHK);   // heavy-first decode
  int ci = ci2;
  int qb = 15;
#pragma unroll
  for (int q = 0; q < 16; q++) {
    const int cnt = (q >> 2) + 1;
    if (ci < cnt) { qb = q; break; }
    ci -= cnt;
  }
  const int slot = bh * NCHK + ci2;             // stable partial-slot id
  const int t0 = qb * 128;
  const int it0 = ci * 8;
  const int it1 = min(it0 + 8, 2 * qb + 2);     // span is even (2..8)

  const int tid = threadIdx.x;
  const int w = tid >> 6;
  const int l = tid & 63;
  const int l31 = l & 31;
  const int lhi = l >> 5;

  bf16x8 qf[4];
  {
    const ushort* qp = Qb + ((size_t)bh * T + t0 + w * 32 + l31) * 64 + 8 * lhi;
#pragma unroll
    for (int kf = 0; kf < 4; kf++) qf[kf] = *(const bf16x8*)(qp + kf * 16);
  }
  f32x16 o0, o1;
#pragma unroll
  for (int r = 0; r < 16; r++) { o0[r] = 0.f; o1[r] = 0.f; }
  float rs0 = 0.f, rs1 = 0.f, rs2 = 0.f, rs3 = 0.f;

  const int sr = tid >> 2;
  const int scg = (tid & 3) * 16;
  const ushort* ksrc = Kb + ((size_t)bh * T + sr) * 64 + scg;
  const ushort* vsrc = Vtb + ((size_t)bh * 64 + sr) * T + scg;
  const int qlo = t0 + w * 32;
  const int qg = qlo + l31;          // this lane's q column

  bf16x8 kA0, kA1, vA0, vA1, kB0, kB1, vB0, vB1;
  {
    const size_t sa = (size_t)it0 * 64, sb = sa + 64;
    kA0 = *(const bf16x8*)(ksrc + sa * 64);
    kA1 = *(const bf16x8*)(ksrc + sa * 64 + 8);
    vA0 = *(const bf16x8*)(vsrc + sa);
    vA1 = *(const bf16x8*)(vsrc + sa + 8);
    kB0 = *(const bf16x8*)(ksrc + sb * 64);
    kB1 = *(const bf16x8*)(ksrc + sb * 64 + 8);
    vB0 = *(const bf16x8*)(vsrc + sb);
    vB1 = *(const bf16x8*)(vsrc + sb + 8);
  }

  auto process = [&](int s0, int ro) {
    f32x16 sA, sB;
#pragma unroll
    for (int r = 0; r < 16; r++) { sA[r] = 0.f; sB[r] = 0.f; }
    __builtin_amdgcn_s_setprio(1);
#pragma unroll
    for (int kf = 0; kf < 4; kf++) {
      const bf16x8 ka  = *(const bf16x8*)&K_lds[ro + l31][kf * 16 + 8 * lhi];
      const bf16x8 kb2 = *(const bf16x8*)&K_lds[ro + 32 + l31][kf * 16 + 8 * lhi];
      sA = __builtin_amdgcn_mfma_f32_32x32x16_bf16(ka, qf[kf], sA, 0, 0, 0);
      sB = __builtin_amdgcn_mfma_f32_32x32x16_bf16(kb2, qf[kf], sB, 0, 0, 0);
    }
    __builtin_amdgcn_s_setprio(0);

    const bool nomask = (s0 + 63 <= qlo);
#pragma unroll
    for (int half = 0; half < 2; half++) {
      float pv[16];
#pragma unroll
      for (int r = 0; r < 16; r++) {
        const int srow = (r & 3) + 8 * (r >> 2) + 4 * lhi;
        const float sv = (half == 0) ? sA[r] : sB[r];
        float p = exp2f(sv * EXP2C);
        if (!nomask && (s0 + half * 32 + srow > qg)) p = 0.f;
        pv[r] = p;
      }
      rs0 += pv[0] + pv[1];  rs1 += pv[2] + pv[3];
      rs2 += pv[4] + pv[5];  rs3 += pv[6] + pv[7];
      rs0 += pv[8] + pv[9];  rs1 += pv[10] + pv[11];
      rs2 += pv[12] + pv[13]; rs3 += pv[14] + pv[15];
#pragma unroll
      for (int sub = 0; sub < 2; sub++) {
        const float* p8 = pv + 8 * sub;
        unsigned X = cvtpk(p8[0], p8[1]);
        unsigned Y = cvtpk(p8[4], p8[5]);
        unsigned Z = cvtpk(p8[2], p8[3]);
        unsigned Wd = cvtpk(p8[6], p8[7]);
        swap32(X, Y);
        swap32(Z, Wd);
        union { unsigned u[4]; bf16x8 v; } fr;
        fr.u[0] = X; fr.u[1] = Z; fr.u[2] = Y; fr.u[3] = Wd;
        const int ksl = half * 2 + sub;
        const bf16x8 va = *(const bf16x8*)&V_lds[ro + l31][ksl * 16 + 8 * lhi];
        const bf16x8 vb = *(const bf16x8*)&V_lds[ro + 32 + l31][ksl * 16 + 8 * lhi];
        __builtin_amdgcn_s_setprio(1);
        o0 = __builtin_amdgcn_mfma_f32_32x32x16_bf16(va, fr.v, o0, 0, 0, 0);
        o1 = __builtin_amdgcn_mfma_f32_32x32x16_bf16(vb, fr.v, o1, 0, 0, 0);
        __builtin_amdgcn_s_setprio(0);
      }
    }
  };

  for (int its = it0; its < it1; its += 2) {
    __syncthreads();
    *(bf16x8*)&K_lds[sr][scg]       = kA0;
    *(bf16x8*)&K_lds[sr][scg + 8]   = kA1;
    *(bf16x8*)&V_lds[sr][scg]       = vA0;
    *(bf16x8*)&V_lds[sr][scg + 8]   = vA1;
    *(bf16x8*)&K_lds[64 + sr][scg]     = kB0;
    *(bf16x8*)&K_lds[64 + sr][scg + 8] = kB1;
    *(bf16x8*)&V_lds[64 + sr][scg]     = vB0;
    *(bf16x8*)&V_lds[64 + sr][scg + 8] = vB1;
    __syncthreads();
    if (its + 2 < it1) {
      const size_t sa = (size_t)(its + 2) * 64, sb = sa + 64;
      kA0 = *(const bf16x8*)(ksrc + sa * 64);
      kA1 = *(const bf16x8*)(ksrc + sa * 64 + 8);
      vA0 = *(const bf16x8*)(vsrc + sa);
      vA1 = *(const bf16x8*)(vsrc + sa + 8);
      kB0 = *(const bf16x8*)(ksrc + sb * 64);
      kB1 = *(const bf16x8*)(ksrc + sb * 64 + 8);
      vB0 = *(const bf16x8*)(vsrc + sb);
      vB1 = *(const bf16x8*)(vsrc + sb + 8);
    }
    const int s0A = its * 64, s0B = s0A + 64;
    if (s0A <= qlo + 31) process(s0A, 0);
    if (s0B <= qlo + 31) process(s0B, 64);
  }

  float rs = (rs0 + rs1) + (rs2 + rs3);
  rs += __shfl_xor(rs, 32);

  const int brow = w * 32 + l31;
  ushort* ob = o_part + ((size_t)slot * 128 + brow) * 64;
  float* rsb = rs_part + (size_t)slot * 128;
#pragma unroll
  for (int r = 0; r < 16; r += 2) {
    const int d = (r & 3) + 8 * (r >> 2) + 4 * lhi;   // even
    *(unsigned*)(ob + d)      = cvtpk(o0[r], o0[r + 1]);
    *(unsigned*)(ob + 32 + d) = cvtpk(o1[r], o1[r + 1]);
  }
  if (l < 32) rsb[brow] = rs;
}

// ------ pass 2: cross-chunk carry + gate computation (verified round 13) -
__global__ __launch_bounds__(256) void gatescan(
    const float* __restrict__ G, const float* __restrict__ Rp,
    const float* __restrict__ pmemg, const float* __restrict__ memg_b,
    const float* __restrict__ mem_scale, float* __restrict__ gate12)
{
  __shared__ float E[8][21];
  const int bh = blockIdx.x;
  const int b = bh / H, h = bh % H;
  const int tid = threadIdx.x;
  if (tid < 21) {
    float e = 0.f;
    const float d256 = 0.076314145f;   // 0.99^256
    for (int c = 0; c < 8; c++) {
      E[c][tid] = e;
      e = DECAY_F * G[((size_t)bh * 8 + c) * 21 + tid] + d256 * e;
    }
  }
  __syncthreads();
  const int chunk = tid >> 5;
  const int base = (tid & 31) * 8;
  float Ec[21];
#pragma unroll
  for (int c = 0; c < 21; c++) Ec[c] = E[chunk][c];

  const float msc = mem_scale[h];
  const float gb = memg_b[h];
  const size_t hb = (size_t)h * NBT + (size_t)b * T;
  const size_t rb = (size_t)b * T;
  float dj = __powf(DECAY_F, (float)base);
  for (int j = 0; j < 8; j++) {
    const int tl = chunk * 256 + base + j;
    const float* rp = Rp + ((size_t)bh * T + tl) * 8;
    const float4 q0 = *(const float4*)rp;
    const float4 q1 = *(const float4*)(rp + 4);
    const float R[6] = { q0.x, q0.y, q0.z, q0.w, q1.x, q1.y };
    const float part1 = q1.z;
    float qd = 0.f;
    {
      int c = 0;
#pragma unroll
      for (int p = 0; p < 6; p++) {
        qd += Ec[c] * R[p] * R[p]; c++;
#pragma unroll
        for (int q = p + 1; q < 6; q++) { qd += 2.f * Ec[c] * R[p] * R[q]; c++; }
      }
    }
    const float score = (part1 + dj * qd) * 0.25f;
    const float g1 = 1.f / (1.f + __expf(-score * msc));
    const float graw = pmemg[hb + tl] + gb;
    const float g2 = 1.f / (1.f + __expf(-graw));
    gate12[(rb + tl) * H + h] = g1 * g2;
    dj *= DECAY_F;
  }
}

// ------- reduce partials + normalize + h-mean gate fuse -> bf16 z --------
__global__ __launch_bounds__(256) void reduce_fuse(
    const ushort* __restrict__ o_part, const float* __restrict__ rs_part,
    const ushort* __restrict__ memv, const float* __restrict__ gate12,
    ushort* __restrict__ zb)
{
  const int idx = blockIdx.x * 256 + threadIdx.x;
  const int row = idx / 96, c = (idx % 96) * 8;
  const int h = c >> 6, d0 = c & 63;
  const int b = row >> 11, tl = row & (T - 1);
  const int qb = tl >> 7, rloc = tl & 127;
  const int g = qb >> 2;
  const int cnt = g + 1;
  const int base = 2 * g * (g + 1) + (qb & 3) * (g + 1);
  const size_t bid0 = (size_t)(b * H + h) * NCHK + base;

  float o[8] = {0.f, 0.f, 0.f, 0.f, 0.f, 0.f, 0.f, 0.f};
  float rsum = 0.f;
  for (int ci = 0; ci < cnt; ci++) {
    const bf16x8 pv = *(const bf16x8*)(o_part + ((bid0 + ci) * 128 + rloc) * 64 + d0);
#pragma unroll
    for (int j = 0; j < 8; j++) o[j] += bf2f((ushort)pv[j]);
    rsum += rs_part[(bid0 + ci) * 128 + rloc];
  }
  const float inv = 1.f / rsum;

  const float* gp = gate12 + (size_t)row * H;
  float gs = 0.f;
#pragma unroll
  for (int j = 0; j < 12; j++) gs += gp[j];
  const float gt = gs * (1.f / 12.f);

  const bf16x8 mv = *(const bf16x8*)(memv + (size_t)row * D + c);
  bf16x8 z;
#pragma unroll
  for (int j = 0; j < 8; j++)
    z[j] = (short)f2bf(o[j] * inv + gt * bf2f((ushort)mv[j]));
  *(bf16x8*)(zb + (size_t)row * D + c) = z;
}

extern "C" void kernel_launch(void* const* d_in, const int* in_sizes, int n_in,
                              void* d_out, int out_size, void* d_ws, size_t ws_size,
                              hipStream_t stream)
{
  const float* x      = (const float*)d_in[0];
  const float* qkv_w  = (const float*)d_in[1];
  const float* qkv_b  = (const float*)d_in[2];
  const float* w1w    = (const float*)d_in[3];
  const float* w2w    = (const float*)d_in[4];
  const float* w1r    = (const float*)d_in[5];
  const float* w2r    = (const float*)d_in[6];
  const float* memv_w = (const float*)d_in[7];
  const float* memv_b = (const float*)d_in[8];
  const float* memg_w = (const float*)d_in[9];
  const float* memg_b = (const float*)d_in[10];
  const float* mem_scale = (const float*)d_in[11];
  const float* out_w  = (const float*)d_in[12];
  const float* out_b  = (const float*)d_in[13];
  float* out = (float*)d_out;

  float* ws    = (float*)d_ws;
  float* pw    = ws;                              // [4][12][4096][4] f32
  float* pmemg = pw + (size_t)4 * H * NBT * 4;    // [12][4096] f32
  float* gate12 = pmemg + (size_t)H * NBT;        // [4096][12] f32
  float* rs_part = gate12 + (size_t)NBT * H;      // [960][128] f32
  float* Rp    = rs_part + (size_t)NBLK_ATTN * 128;  // [24][2048][8] f32
  float* G     = Rp + (size_t)24 * T * 8;         // [24][8][21] f32
  ushort* memv = (ushort*)(G + 24 * 8 * 21 + 24); // [4096][768] bf16 (pad)
  ushort* Xb  = memv + (size_t)NBT * D;           // [4096][768] bf16
  ushort* Wb  = Xb + (size_t)NBT * D;             // cast_all weight rows
  ushort* Qb  = Wb + (size_t)NBT * D;             // [24][2048][64]
  ushort* Kb  = Qb + (size_t)24 * T * 64;
  ushort* Vtb = Kb + (size_t)24 * T * 64;         // [24][64][2048]
  ushort* zb  = Vtb + (size_t)24 * T * 64;        // [4096][768]
  ushort* o_part = zb + (size_t)NBT * D;          // [960][128][64] bf16

  const ushort* W_out = Wb + (size_t)3328 * 768;

  dim3 blk(256);
  cast_all<<<dim3(3072), blk, 0, stream>>>(x, qkv_w, memv_w, out_w,
                                           w1w, w2w, w1r, w2r, memg_w, Xb);

  gemm8_mega<<<dim3(16 * 13), dim3(512), 0, stream>>>(
      Xb, Wb, qkv_b, memv_b, memv, pw, pmemg, Qb, Kb, Vtb);

  attn_memscan<<<dim3(NBLK_MS1 + NBLK_ATTN), blk, 0, stream>>>(
      Qb, Kb, Vtb, o_part, rs_part, pw, Rp, G);

  gatescan<<<dim3(24), blk, 0, stream>>>(G, Rp, pmemg, memg_b, mem_scale, gate12);

  reduce_fuse<<<dim3(NBT * 96 / 256), blk, 0, stream>>>(o_part, rs_part, memv,
                                                        gate12, zb);
  gemm_mfma128<<<dim3(6, 32), blk, 0, stream>>>(zb, W_out, out_b, out, 768);
}

// Round 18
// 107.973 us; speedup vs baseline: 1.1914x; 1.1914x over previous
//
#include <hip/hip_runtime.h>

#define H 12
#define T 2048
#define D 768
#define NBT 4096            // B*T
#define SCALE 0.125f
#define DECAY_F 0.99f
#define NCHK 40             // split-s chunk slots per bh (8 tiles each)
#define NBLK_ATTN (24 * NCHK)
#define EXP2C 0.18033688011f   // 0.125 * log2(e)

typedef __attribute__((ext_vector_type(8))) short bf16x8;
typedef __attribute__((ext_vector_type(4))) float f32x4;
typedef __attribute__((ext_vector_type(16))) float f32x16;

static __device__ __forceinline__ ushort f2bf(float f) {
  union { float f; unsigned u; } v; v.f = f;
  unsigned r = (v.u + 0x7FFFu + ((v.u >> 16) & 1u)) >> 16;
  return (ushort)r;
}
static __device__ __forceinline__ float bf2f(ushort u) {
  union { unsigned u; float f; } v; v.u = ((unsigned)u) << 16;
  return v.f;
}
static __device__ __forceinline__ unsigned cvtpk(float lo, float hi) {
  unsigned r;
  asm("v_cvt_pk_bf16_f32 %0, %1, %2" : "=v"(r) : "v"(lo), "v"(hi));
  return r;
}
static __device__ __forceinline__ void swap32(unsigned &a, unsigned &b) {
  asm("v_permlane32_swap_b32 %0, %1" : "+v"(a), "+v"(b));
}

static __device__ __forceinline__ void gload16(const void* g, void* s) {
  __builtin_amdgcn_global_load_lds(
      (const __attribute__((address_space(1))) unsigned int*)g,
      (__attribute__((address_space(3))) unsigned int*)s, 16, 0, 0);
}

// ---------------- cast x + all weights to bf16 (flat segmented) ----------
__global__ __launch_bounds__(256) void cast_all(
    const float* __restrict__ x, const float* __restrict__ qkv_w,
    const float* __restrict__ memv_w, const float* __restrict__ out_w,
    const float* __restrict__ w1w, const float* __restrict__ w2w,
    const float* __restrict__ w1r, const float* __restrict__ w2r,
    const float* __restrict__ memg_w, ushort* __restrict__ dst)
{
  const size_t i8 = ((size_t)blockIdx.x * 256 + threadIdx.x) * 8;
  const float* src; size_t off;
  if      (i8 < 3145728) { src = x;      off = i8; }
  else if (i8 < 4915200) { src = qkv_w;  off = i8 - 3145728; }
  else if (i8 < 5505024) { src = memv_w; off = i8 - 4915200; }
  else if (i8 < 5541888) { src = w1w;    off = i8 - 5505024; }
  else if (i8 < 5578752) { src = w2w;    off = i8 - 5541888; }
  else if (i8 < 5615616) { src = w1r;    off = i8 - 5578752; }
  else if (i8 < 5652480) { src = w2r;    off = i8 - 5615616; }
  else if (i8 < 5661696) { src = memg_w; off = i8 - 5652480; }
  else if (i8 < 5701632) { *(uint4*)(dst + i8) = make_uint4(0, 0, 0, 0); return; }
  else                   { src = out_w;  off = i8 - 5701632; }
  const float4 a = *(const float4*)(src + off);
  const float4 b = *(const float4*)(src + off + 4);
  bf16x8 o;
  o[0] = (short)f2bf(a.x); o[1] = (short)f2bf(a.y);
  o[2] = (short)f2bf(a.z); o[3] = (short)f2bf(a.w);
  o[4] = (short)f2bf(b.x); o[5] = (short)f2bf(b.y);
  o[6] = (short)f2bf(b.z); o[7] = (short)f2bf(b.w);
  *(bf16x8*)(dst + i8) = o;
}

// ============ 8-phase 256x256 MFMA GEMM (mega epilogue) ===================
__global__ __launch_bounds__(512, 2) void gemm8_mega(
    const ushort* __restrict__ A, const ushort* __restrict__ W,
    const float* __restrict__ qkv_b, const float* __restrict__ memv_b,
    ushort* __restrict__ memvp, float* __restrict__ pw,
    float* __restrict__ pmemg,
    ushort* __restrict__ Qb, ushort* __restrict__ Kb, ushort* __restrict__ Vtb)
{
  __shared__ ushort lds[65536];   // 128 KiB
  const int tid = threadIdx.x;
  const int w = tid >> 6, l = tid & 63;
  const int wm = w >> 2, wn = w & 3;
  const int l15 = l & 15, l4 = l >> 4;

  int bid = blockIdx.x;
  bid = (bid & 7) * 26 + (bid >> 3);
  const int bx = bid % 13, by = bid / 13;
  const int bm = by * 256, bn = bx * 256;

  f32x4 acc[8][4];
#pragma unroll
  for (int i = 0; i < 8; i++)
#pragma unroll
    for (int j = 0; j < 4; j++) acc[i][j] = (f32x4){0.f, 0.f, 0.f, 0.f};

  auto stage = [&](int s, int isB, int h, int kt) {
    const ushort* src = (isB ? W + (size_t)bn * 768 : A + (size_t)bm * 768);
#pragma unroll
    for (int j = 0; j < 2; j++) {
      const int chunk = j * 512 + tid;
      const int r = chunk >> 3, c = chunk & 7;
      const int csrc = c ^ (r & 7);
      gload16(src + (size_t)(h * 128 + r) * 768 + kt * 64 + csrc * 8,
              (char*)lds + s * 65536 + isB * 32768 + h * 16384
                         + (size_t)(j * 512 + w * 64) * 16);
    }
  };
  auto rdA = [&](int s, int mi, int ks) -> bf16x8 {
    const int row = wm * 128 + mi * 16 + l15;
    const int ch = (ks * 4 + l4) ^ (l15 & 7);
    return *(const bf16x8*)((const char*)lds + s * 65536 + row * 128 + ch * 16);
  };
  auto rdB = [&](int s, int ni, int ks) -> bf16x8 {
    const int row = wn * 64 + ni * 16 + l15;
    const int ch = (ks * 4 + l4) ^ (l15 & 7);
    return *(const bf16x8*)((const char*)lds + s * 65536 + 32768 + row * 128 + ch * 16);
  };

  stage(0, 1, 0, 0); stage(0, 1, 1, 0); stage(0, 0, 0, 0); stage(0, 0, 1, 0);

#define MFMA_QUAD(mb, ks)                                                      \
  {                                                                            \
    __builtin_amdgcn_s_setprio(1);                                             \
    _Pragma("unroll")                                                          \
    for (int mi = 0; mi < 4; mi++) {                                           \
      const bf16x8 av = rdA(s, (mb) + mi, (ks));                               \
      acc[(mb)+mi][0] = __builtin_amdgcn_mfma_f32_16x16x32_bf16(av, bq0, acc[(mb)+mi][0], 0, 0, 0); \
      acc[(mb)+mi][1] = __builtin_amdgcn_mfma_f32_16x16x32_bf16(av, bq1, acc[(mb)+mi][1], 0, 0, 0); \
      acc[(mb)+mi][2] = __builtin_amdgcn_mfma_f32_16x16x32_bf16(av, bq2, acc[(mb)+mi][2], 0, 0, 0); \
      acc[(mb)+mi][3] = __builtin_amdgcn_mfma_f32_16x16x32_bf16(av, bq3, acc[(mb)+mi][3], 0, 0, 0); \
    }                                                                          \
    __builtin_amdgcn_s_setprio(0);                                             \
  }

  for (int t = 0; t < 12; t++) {
    const int s = t & 1, sn = s ^ 1;
    const int ktn = (t + 1) % 12;
    bf16x8 bq0, bq1, bq2, bq3;
    stage(sn, 1, 0, ktn);
    asm volatile("s_waitcnt vmcnt(2)" ::: "memory");
    __builtin_amdgcn_s_barrier();
    __builtin_amdgcn_sched_barrier(0);
    bq0 = rdB(s, 0, 0); bq1 = rdB(s, 1, 0); bq2 = rdB(s, 2, 0); bq3 = rdB(s, 3, 0);
    MFMA_QUAD(0, 0);
    __builtin_amdgcn_s_barrier();
    stage(sn, 1, 1, ktn);
    MFMA_QUAD(4, 0);
    __builtin_amdgcn_s_barrier();
    stage(sn, 0, 0, ktn);
    bq0 = rdB(s, 0, 1); bq1 = rdB(s, 1, 1); bq2 = rdB(s, 2, 1); bq3 = rdB(s, 3, 1);
    MFMA_QUAD(0, 1);
    __builtin_amdgcn_s_barrier();
    stage(sn, 0, 1, ktn);
    MFMA_QUAD(4, 1);
    __builtin_amdgcn_s_barrier();
  }

#pragma unroll
  for (int mi = 0; mi < 8; mi++) {
    const int row0 = bm + wm * 128 + mi * 16 + l4 * 4;
    const int b = row0 >> 11, tl = row0 & (T - 1);
#pragma unroll
    for (int ni = 0; ni < 4; ni++) {
      const int col = bn + wn * 64 + ni * 16 + l15;
      const f32x4 a4 = acc[mi][ni];
      if (col < 2304) {
        const float bv = qkv_b[col];
        const int sec = col / 768, cm = col % 768;
        const int h = cm >> 6, d = cm & 63;
        if (sec < 2) {
          ushort* dst = sec ? Kb : Qb;
#pragma unroll
          for (int r = 0; r < 4; r++)
            dst[((size_t)(b * H + h) * T + tl + r) * 64 + d] = f2bf(a4[r] + bv);
        } else {
          uint2 u;
          u.x = (unsigned)f2bf(a4[0] + bv) | ((unsigned)f2bf(a4[1] + bv) << 16);
          u.y = (unsigned)f2bf(a4[2] + bv) | ((unsigned)f2bf(a4[3] + bv) << 16);
          *(uint2*)(Vtb + ((size_t)(b * H + h) * 64 + d) * T + tl) = u;
        }
      } else if (col < 3072) {
        const int c2 = col - 2304;
        const float bv = memv_b[c2];
#pragma unroll
        for (int r = 0; r < 4; r++)
          memvp[(size_t)(row0 + r) * 768 + c2] = f2bf(a4[r] + bv);
      } else if (col < 3276) {
        const int c2 = col - 3072;
        if (c2 < 192) {
          float* pb = pw + (size_t)(c2 / 48) * (H * NBT * 4);
          const int hh = (c2 % 48) >> 2, comp = c2 & 3;
#pragma unroll
          for (int r = 0; r < 4; r++)
            pb[((size_t)hh * NBT + row0 + r) * 4 + comp] = a4[r];
        } else {
#pragma unroll
          for (int r = 0; r < 4; r++)
            pmemg[(size_t)(c2 - 192) * NBT + row0 + r] = a4[r];
        }
      }
    }
  }
}

// ---------------- 128x128 MFMA GEMM (fp32 C + bias) — out-projection ------
__global__ __launch_bounds__(256) void gemm_mfma128(
    const ushort* __restrict__ A, const ushort* __restrict__ W,
    const float* __restrict__ bias, float* __restrict__ C, int ldc)
{
  __shared__ ushort A_lds[128 * 64];
  __shared__ ushort B_lds[128 * 64];
  const int tid = threadIdx.x;
  const int w = tid >> 6, l = tid & 63;
  const int wm = w >> 1, wn = w & 1;
  const int bm = blockIdx.y * 128, bn = blockIdx.x * 128;
  const int l15 = l & 15, l4 = l >> 4;

  f32x4 acc[4][4];
#pragma unroll
  for (int i = 0; i < 4; i++)
#pragma unroll
    for (int j = 0; j < 4; j++) acc[i][j] = (f32x4){0.f, 0.f, 0.f, 0.f};

  const int srow = w * 32 + (l >> 3);
  const int scol = (l & 7) * 8;
  const ushort* Ag = A + (size_t)(bm + srow) * 768 + scol;
  const ushort* Wg = W + (size_t)(bn + srow) * 768 + scol;
  ushort* Asl = &A_lds[(w * 32) * 64];
  ushort* Bsl = &B_lds[(w * 32) * 64];

  for (int k0 = 0; k0 < 768; k0 += 64) {
#pragma unroll
    for (int i = 0; i < 4; i++) {
      gload16(Ag + k0 + i * 8 * 768, Asl + i * 8 * 64);
      gload16(Wg + k0 + i * 8 * 768, Bsl + i * 8 * 64);
    }
    __syncthreads();
#pragma unroll
    for (int ks = 0; ks < 2; ks++) {
      bf16x8 af[4], bfr[4];
#pragma unroll
      for (int i = 0; i < 4; i++) {
        af[i]  = *(const bf16x8*)&A_lds[(wm * 64 + i * 16 + l15) * 64 + ks * 32 + l4 * 8];
        bfr[i] = *(const bf16x8*)&B_lds[(wn * 64 + i * 16 + l15) * 64 + ks * 32 + l4 * 8];
      }
#pragma unroll
      for (int mi = 0; mi < 4; mi++)
#pragma unroll
        for (int ni = 0; ni < 4; ni++)
          acc[mi][ni] = __builtin_amdgcn_mfma_f32_16x16x32_bf16(af[mi], bfr[ni], acc[mi][ni], 0, 0, 0);
    }
    __syncthreads();
  }
#pragma unroll
  for (int mi = 0; mi < 4; mi++) {
    const int row0 = bm + wm * 64 + mi * 16 + l4 * 4;
#pragma unroll
    for (int ni = 0; ni < 4; ni++) {
      const int col = bn + wn * 64 + ni * 16 + l15;
      const float bv = bias[col];
#pragma unroll
      for (int r = 0; r < 4; r++)
        C[(size_t)(row0 + r) * ldc + col] = acc[mi][ni][r] + bv;
    }
  }
}

// ---------------- Plucker memory scan body (fused, runs FIRST) -----------
__device__ __forceinline__ void ext_norm6(const float4 a, const float4 b, float* L)
{
  L[0] = a.x * b.y - a.y * b.x;
  L[1] = a.x * b.z - a.z * b.x;
  L[2] = a.x * b.w - a.w * b.x;
  L[3] = a.y * b.z - a.z * b.y;
  L[4] = a.y * b.w - a.w * b.y;
  L[5] = a.z * b.w - a.w * b.z;
  float n2 = L[0]*L[0] + L[1]*L[1] + L[2]*L[2] + L[3]*L[3] + L[4]*L[4] + L[5]*L[5];
  float n = fmaxf(sqrtf(n2), 1e-12f);
  float inv = 1.f / n;
#pragma unroll
  for (int i = 0; i < 6; i++) L[i] *= inv;
}

// pw: [4][H][NBT][4] f32 head-major; pmemg: [H][NBT]
static __device__ void memscan_body(
    int bb, char* smem,
    const float* __restrict__ pw, const float* __restrict__ pmemg,
    const float* __restrict__ memg_b, const float* __restrict__ mem_scale,
    float* __restrict__ gate12)
{
  const int b = bb / H, h = bb % H;
  const int tid = threadIdx.x;
  float (*S)[22] = (float(*)[22])smem;
  const int base = tid * 8;
  const size_t hb = (size_t)h * NBT + (size_t)b * T;
  const float* pw1w = pw + 0 * (size_t)(H * NBT * 4) + hb * 4;
  const float* pw2w = pw + 1 * (size_t)(H * NBT * 4) + hb * 4;
  const float* pw1r = pw + 2 * (size_t)(H * NBT * 4) + hb * 4;
  const float* pw2r = pw + 3 * (size_t)(H * NBT * 4) + hb * 4;

  float M[21];
#pragma unroll
  for (int c = 0; c < 21; c++) M[c] = 0.f;
  float sloc[8];

  for (int j = 0; j < 8; j++) {
    const int t = base + j;
    const float4 w2 = *(const float4*)(pw2w + (size_t)t * 4);
    float C[21];
#pragma unroll
    for (int c = 0; c < 21; c++) C[c] = 0.f;
    const int offs[4] = {1, 2, 4, 8};
#pragma unroll
    for (int oi = 0; oi < 4; oi++) {
      const int off = offs[oi];
      if (t >= off) {
        const float4 w1 = *(const float4*)(pw1w + (size_t)(t - off) * 4);
        float L[6];
        ext_norm6(w1, w2, L);
        const float Jv[6] = { L[5], -L[4], L[3], L[2], -L[1], L[0] };
        int c = 0;
#pragma unroll
        for (int p = 0; p < 6; p++)
#pragma unroll
          for (int q = p; q < 6; q++) { C[c] += Jv[p] * Jv[q]; c++; }
      }
    }
    float R[6];
    {
      const float4 r1 = *(const float4*)(pw1r + (size_t)t * 4);
      const float4 r2 = *(const float4*)(pw2r + (size_t)t * 4);
      ext_norm6(r1, r2, R);
    }
    float qd = 0.f;
    {
      int c = 0;
#pragma unroll
      for (int p = 0; p < 6; p++) {
        qd += M[c] * R[p] * R[p]; c++;
#pragma unroll
        for (int q = p + 1; q < 6; q++) { qd += 2.f * M[c] * R[p] * R[q]; c++; }
      }
    }
    sloc[j] = qd;
#pragma unroll
    for (int cc = 0; cc < 21; cc++) M[cc] = DECAY_F * (M[cc] + C[cc]);
  }

#pragma unroll
  for (int c = 0; c < 21; c++) S[tid][c] = M[c];
  __syncthreads();
  float p8 = 0.92274469442792013f;  // 0.99^8, squared each level
  for (int off = 1; off < 256; off <<= 1) {
    float tmpv[21];
#pragma unroll
    for (int c = 0; c < 21; c++) tmpv[c] = (tid >= off) ? S[tid - off][c] : 0.f;
    __syncthreads();
#pragma unroll
    for (int c = 0; c < 21; c++) S[tid][c] += p8 * tmpv[c];
    __syncthreads();
    p8 *= p8;
  }
  float P[21];
#pragma unroll
  for (int c = 0; c < 21; c++) P[c] = (tid > 0) ? S[tid - 1][c] : 0.f;

  const float msc = mem_scale[h];
  const float gb = memg_b[h];
  const size_t rb = (size_t)b * T;
  float dj = 1.f;
  for (int j = 0; j < 8; j++) {
    const int t = base + j;
    float R[6];
    {
      const float4 r1 = *(const float4*)(pw1r + (size_t)t * 4);
      const float4 r2 = *(const float4*)(pw2r + (size_t)t * 4);
      ext_norm6(r1, r2, R);
    }
    float qd = 0.f;
    {
      int c = 0;
#pragma unroll
      for (int p = 0; p < 6; p++) {
        qd += P[c] * R[p] * R[p]; c++;
#pragma unroll
        for (int q = p + 1; q < 6; q++) { qd += 2.f * P[c] * R[p] * R[q]; c++; }
      }
    }
    const float score = (sloc[j] + dj * qd) * 0.25f;
    const float g1 = 1.f / (1.f + __expf(-score * msc));
    const float graw = pmemg[hb + t] + gb;
    const float g2 = 1.f / (1.f + __expf(-graw));
    gate12[(rb + t) * H + h] = g1 * g2;
    dj *= DECAY_F;
  }
}

// ------ fused: memscan (blocks 0-23, start first) + flash attention ------
// attn: split-8 chunks; bh-clustered XCD decode (xcd = abid&7 owns 3 bhs),
// heavy-first within each bh. slot id from decoded (bh, ci2) — unchanged.
__global__ __launch_bounds__(256) void attn_memscan(
    const ushort* __restrict__ Qb, const ushort* __restrict__ Kb,
    const ushort* __restrict__ Vtb, ushort* __restrict__ o_part,
    float* __restrict__ rs_part,
    const float* __restrict__ pw, const float* __restrict__ pmemg,
    const float* __restrict__ memg_b, const float* __restrict__ mem_scale,
    float* __restrict__ gate12)
{
  __shared__ __align__(16) char smem[36864];   // attn: K/V tiles; memscan: S

  if (blockIdx.x < 24) {
    memscan_body(blockIdx.x, smem, pw, pmemg, memg_b, mem_scale, gate12);
    return;
  }
  const int abid = blockIdx.x - 24;

  typedef ushort row72[72];
  row72* K_lds = (row72*)smem;                  // [128][72]
  row72* V_lds = (row72*)(smem + 18432);        // [128][72]

  // bh-clustered XCD decode: consecutive blocks on one XCD share bh -> K/V L2-resident
  const int xcd = abid & 7;
  const int j = abid >> 3;                      // 0..119
  const int bh = xcd + 8 * (j / NCHK);
  const int ci2 = (NCHK - 1) - (j % NCHK);      // heavy-first within bh
  int ci = ci2;
  int qb = 15;
#pragma unroll
  for (int q = 0; q < 16; q++) {
    const int cnt = (q >> 2) + 1;
    if (ci < cnt) { qb = q; break; }
    ci -= cnt;
  }
  const int slot = bh * NCHK + ci2;             // stable partial-slot id
  const int t0 = qb * 128;
  const int it0 = ci * 8;
  const int it1 = min(it0 + 8, 2 * qb + 2);     // span is even (2..8)

  const int tid = threadIdx.x;
  const int w = tid >> 6;
  const int l = tid & 63;
  const int l31 = l & 31;
  const int lhi = l >> 5;

  bf16x8 qf[4];
  {
    const ushort* qp = Qb + ((size_t)bh * T + t0 + w * 32 + l31) * 64 + 8 * lhi;
#pragma unroll
    for (int kf = 0; kf < 4; kf++) qf[kf] = *(const bf16x8*)(qp + kf * 16);
  }
  f32x16 o0, o1;
#pragma unroll
  for (int r = 0; r < 16; r++) { o0[r] = 0.f; o1[r] = 0.f; }
  float rs0 = 0.f, rs1 = 0.f, rs2 = 0.f, rs3 = 0.f;

  const int sr = tid >> 2;
  const int scg = (tid & 3) * 16;
  const ushort* ksrc = Kb + ((size_t)bh * T + sr) * 64 + scg;
  const ushort* vsrc = Vtb + ((size_t)bh * 64 + sr) * T + scg;
  const int qlo = t0 + w * 32;
  const int qg = qlo + l31;          // this lane's q column

  bf16x8 kA0, kA1, vA0, vA1, kB0, kB1, vB0, vB1;
  {
    const size_t sa = (size_t)it0 * 64, sb = sa + 64;
    kA0 = *(const bf16x8*)(ksrc + sa * 64);
    kA1 = *(const bf16x8*)(ksrc + sa * 64 + 8);
    vA0 = *(const bf16x8*)(vsrc + sa);
    vA1 = *(const bf16x8*)(vsrc + sa + 8);
    kB0 = *(const bf16x8*)(ksrc + sb * 64);
    kB1 = *(const bf16x8*)(ksrc + sb * 64 + 8);
    vB0 = *(const bf16x8*)(vsrc + sb);
    vB1 = *(const bf16x8*)(vsrc + sb + 8);
  }

  auto process = [&](int s0, int ro) {
    f32x16 sA, sB;
#pragma unroll
    for (int r = 0; r < 16; r++) { sA[r] = 0.f; sB[r] = 0.f; }
    __builtin_amdgcn_s_setprio(1);
#pragma unroll
    for (int kf = 0; kf < 4; kf++) {
      const bf16x8 ka  = *(const bf16x8*)&K_lds[ro + l31][kf * 16 + 8 * lhi];
      const bf16x8 kb2 = *(const bf16x8*)&K_lds[ro + 32 + l31][kf * 16 + 8 * lhi];
      sA = __builtin_amdgcn_mfma_f32_32x32x16_bf16(ka, qf[kf], sA, 0, 0, 0);
      sB = __builtin_amdgcn_mfma_f32_32x32x16_bf16(kb2, qf[kf], sB, 0, 0, 0);
    }
    __builtin_amdgcn_s_setprio(0);

    const bool nomask = (s0 + 63 <= qlo);
#pragma unroll
    for (int half = 0; half < 2; half++) {
      float pv[16];
#pragma unroll
      for (int r = 0; r < 16; r++) {
        const int srow = (r & 3) + 8 * (r >> 2) + 4 * lhi;
        const float sv = (half == 0) ? sA[r] : sB[r];
        float p = exp2f(sv * EXP2C);
        if (!nomask && (s0 + half * 32 + srow > qg)) p = 0.f;
        pv[r] = p;
      }
      rs0 += pv[0] + pv[1];  rs1 += pv[2] + pv[3];
      rs2 += pv[4] + pv[5];  rs3 += pv[6] + pv[7];
      rs0 += pv[8] + pv[9];  rs1 += pv[10] + pv[11];
      rs2 += pv[12] + pv[13]; rs3 += pv[14] + pv[15];
#pragma unroll
      for (int sub = 0; sub < 2; sub++) {
        const float* p8 = pv + 8 * sub;
        unsigned X = cvtpk(p8[0], p8[1]);
        unsigned Y = cvtpk(p8[4], p8[5]);
        unsigned Z = cvtpk(p8[2], p8[3]);
        unsigned Wd = cvtpk(p8[6], p8[7]);
        swap32(X, Y);
        swap32(Z, Wd);
        union { unsigned u[4]; bf16x8 v; } fr;
        fr.u[0] = X; fr.u[1] = Z; fr.u[2] = Y; fr.u[3] = Wd;
        const int ksl = half * 2 + sub;
        const bf16x8 va = *(const bf16x8*)&V_lds[ro + l31][ksl * 16 + 8 * lhi];
        const bf16x8 vb = *(const bf16x8*)&V_lds[ro + 32 + l31][ksl * 16 + 8 * lhi];
        __builtin_amdgcn_s_setprio(1);
        o0 = __builtin_amdgcn_mfma_f32_32x32x16_bf16(va, fr.v, o0, 0, 0, 0);
        o1 = __builtin_amdgcn_mfma_f32_32x32x16_bf16(vb, fr.v, o1, 0, 0, 0);
        __builtin_amdgcn_s_setprio(0);
      }
    }
  };

  for (int its = it0; its < it1; its += 2) {
    __syncthreads();
    *(bf16x8*)&K_lds[sr][scg]       = kA0;
    *(bf16x8*)&K_lds[sr][scg + 8]   = kA1;
    *(bf16x8*)&V_lds[sr][scg]       = vA0;
    *(bf16x8*)&V_lds[sr][scg + 8]   = vA1;
    *(bf16x8*)&K_lds[64 + sr][scg]     = kB0;
    *(bf16x8*)&K_lds[64 + sr][scg + 8] = kB1;
    *(bf16x8*)&V_lds[64 + sr][scg]     = vB0;
    *(bf16x8*)&V_lds[64 + sr][scg + 8] = vB1;
    __syncthreads();
    if (its + 2 < it1) {
      const size_t sa = (size_t)(its + 2) * 64, sb = sa + 64;
      kA0 = *(const bf16x8*)(ksrc + sa * 64);
      kA1 = *(const bf16x8*)(ksrc + sa * 64 + 8);
      vA0 = *(const bf16x8*)(vsrc + sa);
      vA1 = *(const bf16x8*)(vsrc + sa + 8);
      kB0 = *(const bf16x8*)(ksrc + sb * 64);
      kB1 = *(const bf16x8*)(ksrc + sb * 64 + 8);
      vB0 = *(const bf16x8*)(vsrc + sb);
      vB1 = *(const bf16x8*)(vsrc + sb + 8);
    }
    const int s0A = its * 64, s0B = s0A + 64;
    if (s0A <= qlo + 31) process(s0A, 0);
    if (s0B <= qlo + 31) process(s0B, 64);
  }

  float rs = (rs0 + rs1) + (rs2 + rs3);
  rs += __shfl_xor(rs, 32);

  const int brow = w * 32 + l31;
  ushort* ob = o_part + ((size_t)slot * 128 + brow) * 64;
  float* rsb = rs_part + (size_t)slot * 128;
#pragma unroll
  for (int r = 0; r < 16; r += 2) {
    const int d = (r & 3) + 8 * (r >> 2) + 4 * lhi;   // even
    *(unsigned*)(ob + d)      = cvtpk(o0[r], o0[r + 1]);
    *(unsigned*)(ob + 32 + d) = cvtpk(o1[r], o1[r + 1]);
  }
  if (l < 32) rsb[brow] = rs;
}

// ------- reduce partials + normalize + h-mean gate fuse -> bf16 z --------
__global__ __launch_bounds__(256) void reduce_fuse(
    const ushort* __restrict__ o_part, const float* __restrict__ rs_part,
    const ushort* __restrict__ memv, const float* __restrict__ gate12,
    ushort* __restrict__ zb)
{
  const int idx = blockIdx.x * 256 + threadIdx.x;
  const int row = idx / 96, c = (idx % 96) * 8;
  const int h = c >> 6, d0 = c & 63;
  const int b = row >> 11, tl = row & (T - 1);
  const int qb = tl >> 7, rloc = tl & 127;
  const int g = qb >> 2;
  const int cnt = g + 1;
  const int base = 2 * g * (g + 1) + (qb & 3) * (g + 1);
  const size_t bid0 = (size_t)(b * H + h) * NCHK + base;

  float o[8] = {0.f, 0.f, 0.f, 0.f, 0.f, 0.f, 0.f, 0.f};
  float rsum = 0.f;
  for (int ci = 0; ci < cnt; ci++) {
    const bf16x8 pv = *(const bf16x8*)(o_part + ((bid0 + ci) * 128 + rloc) * 64 + d0);
#pragma unroll
    for (int j = 0; j < 8; j++) o[j] += bf2f((ushort)pv[j]);
    rsum += rs_part[(bid0 + ci) * 128 + rloc];
  }
  const float inv = 1.f / rsum;

  const float* gp = gate12 + (size_t)row * H;
  float gs = 0.f;
#pragma unroll
  for (int j = 0; j < 12; j++) gs += gp[j];
  const float gt = gs * (1.f / 12.f);

  const bf16x8 mv = *(const bf16x8*)(memv + (size_t)row * D + c);
  bf16x8 z;
#pragma unroll
  for (int j = 0; j < 8; j++)
    z[j] = (short)f2bf(o[j] * inv + gt * bf2f((ushort)mv[j]));
  *(bf16x8*)(zb + (size_t)row * D + c) = z;
}

extern "C" void kernel_launch(void* const* d_in, const int* in_sizes, int n_in,
                              void* d_out, int out_size, void* d_ws, size_t ws_size,
                              hipStream_t stream)
{
  const float* x      = (const float*)d_in[0];
  const float* qkv_w  = (const float*)d_in[1];
  const float* qkv_b  = (const float*)d_in[2];
  const float* w1w    = (const float*)d_in[3];
  const float* w2w    = (const float*)d_in[4];
  const float* w1r    = (const float*)d_in[5];
  const float* w2r    = (const float*)d_in[6];
  const float* memv_w = (const float*)d_in[7];
  const float* memv_b = (const float*)d_in[8];
  const float* memg_w = (const float*)d_in[9];
  const float* memg_b = (const float*)d_in[10];
  const float* mem_scale = (const float*)d_in[11];
  const float* out_w  = (const float*)d_in[12];
  const float* out_b  = (const float*)d_in[13];
  float* out = (float*)d_out;

  float* ws    = (float*)d_ws;
  float* pw    = ws;                              // [4][12][4096][4] f32
  float* pmemg = pw + (size_t)4 * H * NBT * 4;    // [12][4096] f32
  float* gate12 = pmemg + (size_t)H * NBT;        // [4096][12] f32
  float* rs_part = gate12 + (size_t)NBT * H;      // [960][128] f32
  ushort* memv = (ushort*)(rs_part + (size_t)NBLK_ATTN * 128); // [4096][768] bf16
  ushort* Xb  = memv + (size_t)NBT * D;           // [4096][768] bf16
  ushort* Wb  = Xb + (size_t)NBT * D;             // cast_all weight rows
  ushort* Qb  = Wb + (size_t)NBT * D;             // [24][2048][64]
  ushort* Kb  = Qb + (size_t)24 * T * 64;
  ushort* Vtb = Kb + (size_t)24 * T * 64;         // [24][64][2048]
  ushort* zb  = Vtb + (size_t)24 * T * 64;        // [4096][768]
  ushort* o_part = zb + (size_t)NBT * D;          // [960][128][64] bf16

  const ushort* W_out = Wb + (size_t)3328 * 768;

  dim3 blk(256);
  cast_all<<<dim3(3072), blk, 0, stream>>>(x, qkv_w, memv_w, out_w,
                                           w1w, w2w, w1r, w2r, memg_w, Xb);

  gemm8_mega<<<dim3(16 * 13), dim3(512), 0, stream>>>(
      Xb, Wb, qkv_b, memv_b, memv, pw, pmemg, Qb, Kb, Vtb);

  attn_memscan<<<dim3(NBLK_ATTN + 24), blk, 0, stream>>>(
      Qb, Kb, Vtb, o_part, rs_part, pw, pmemg, memg_b, mem_scale, gate12);

  reduce_fuse<<<dim3(NBT * 96 / 256), blk, 0, stream>>>(o_part, rs_part, memv,
                                                        gate12, zb);
  gemm_mfma128<<<dim3(6, 32), blk, 0, stream>>>(zb, W_out, out_b, out, 768);
}